// Round 6
// baseline (155.692 us; speedup 1.0000x reference)
//
#include <hip/hip_runtime.h>
#include <cstdint>
#include <cstddef>

#define VOCAB 50000
#define EMBED 256
#define BATCH 16384
#define NSAMP 4096

typedef float f32x4 __attribute__((ext_vector_type(4)));
typedef int   i32x8 __attribute__((ext_vector_type(8)));

// ---------- helpers ----------

// Pure-HW log(expected_count): no libm calls.
//   p = log1p(1/(id+1)) / log(V+1)           (log1p via __logf(1+u), u>=2e-5)
//   q = NSAMP * log1p(-p)                    (5-term series, p <= 0.0641)
//   lec = log(1 - e^q)                       (q in [-272, -0.0075])
// Worst-case abs err ~3e-3 (from 1+u rounding at large id) — negligible here.
__device__ __forceinline__ float log_expected_count(int id) {
    float u = 1.0f / ((float)id + 1.0f);
    float a = __logf(1.0f + u);
    float p = a * 0.09242324f;   // 1/log(50001)
    float ser = p * (1.0f + p * (0.5f + p * (0.33333333f + p * (0.25f + p * 0.2f))));
    float q = -(float)NSAMP * ser;
    return __logf(1.0f - __expf(q));
}

// softplus(x) = max(x,0) + log1p(e^{-|x|}); deg-5 minimax (|err|<=1e-5)
__device__ __forceinline__ float softplus_f(float x) {
    float v = __expf(-fabsf(x));
    float p = fmaf(v, 0.03215845f, -0.13606275f);
    p = fmaf(v, p, 0.28947478f);
    p = fmaf(v, p, -0.49190896f);
    p = fmaf(v, p, 0.99949556f);
    return fmaxf(x, 0.0f) + v * p;
}

// pack 4 floats -> 4 fp8 e4m3 bytes (HW cvt, OCP on gfx950)
__device__ __forceinline__ int pk4_fp8(float a, float b, float c, float d) {
    int v = __builtin_amdgcn_cvt_pk_fp8_f32(a, b, 0, false);
    v = __builtin_amdgcn_cvt_pk_fp8_f32(c, d, v, true);
    return v;
}

// Fragment-order layout for an R x 256 fp8 matrix:
//   offset(r,k) = (r>>4)*4096 + (k>>5)*512 + (r&15)*32 + (k&31)
// Wave frag (group g, k-step s): contiguous 2KB at g*4096 + s*2048,
// per-lane 32B at +lane*32 (lane&15 = row, lane>>4 = k-quad).

// ---------- kernels ----------

// blocks [0,1024): true logits + E -> fp8 fragments (1 wave = 4 rows)
// blocks [1024,1088): gather W[sids] * 16 -> fp8 fragments + badj
__global__ __launch_bounds__(256) void k_prep(
        const float* __restrict__ E, const int* __restrict__ tgt,
        const int* __restrict__ sids, const float* __restrict__ W,
        const float* __restrict__ bias,
        unsigned char* __restrict__ EF, unsigned char* __restrict__ BF,
        float* __restrict__ badj, double* __restrict__ pTrue)
{
    const int blk = blockIdx.x, tid = threadIdx.x;
    const int wave = tid >> 6, lane = tid & 63;

    if (blk < 1024) {
        float tsum = 0.0f;
        #pragma unroll
        for (int i = 0; i < 4; ++i) {
            int b = (blk * 4 + wave) + 4096 * i;
            int label = tgt[b];
            float4 e  = ((const float4*)(E + (size_t)b * EMBED))[lane];
            float4 wv = ((const float4*)(W + (size_t)label * EMBED))[lane];
            int pk = pk4_fp8(e.x, e.y, e.z, e.w);
            *(int*)(EF + ((b >> 4) * 4096 + (lane >> 3) * 512
                          + (b & 15) * 32 + (lane & 7) * 4)) = pk;
            float d = e.x * wv.x + e.y * wv.y + e.z * wv.z + e.w * wv.w;
            #pragma unroll
            for (int off = 32; off > 0; off >>= 1) d += __shfl_down(d, off, 64);
            if (lane == 0) {
                float tl = d + bias[label] - log_expected_count(label);
                tsum += softplus_f(-tl);
            }
        }
        __shared__ float ts[4];
        if (lane == 0) ts[wave] = tsum;
        __syncthreads();
        if (tid == 0) pTrue[blk] = (double)((ts[0] + ts[1]) + (ts[2] + ts[3]));
    } else {
        #pragma unroll
        for (int i = 0; i < 4; ++i) {
            int task = (blk - 1024) * 256 + tid + 16384 * i;
            int s = task >> 4, p = task & 15;   // p = 16B chunk, k = p*16
            int sid = sids[s];
            const float4* wr = (const float4*)(W + (size_t)sid * EMBED + p * 16);
            float4 w0 = wr[0], w1 = wr[1], w2 = wr[2], w3 = wr[3];
            int4 o;
            o.x = pk4_fp8(w0.x * 16.0f, w0.y * 16.0f, w0.z * 16.0f, w0.w * 16.0f);
            o.y = pk4_fp8(w1.x * 16.0f, w1.y * 16.0f, w1.z * 16.0f, w1.w * 16.0f);
            o.z = pk4_fp8(w2.x * 16.0f, w2.y * 16.0f, w2.z * 16.0f, w2.w * 16.0f);
            o.w = pk4_fp8(w3.x * 16.0f, w3.y * 16.0f, w3.z * 16.0f, w3.w * 16.0f);
            *(int4*)(BF + ((s >> 4) * 4096 + (p >> 1) * 512
                           + (s & 15) * 32 + (p & 1) * 16)) = o;
            if (p == 0) badj[s] = bias[sid] - log_expected_count(sid);
        }
    }
}

// GEMM: direct-register MX-fp8, no LDS. A (64 rows) resident in 64 VGPRs per
// wave; j-loop over 8 B-tiles with register double-buffered B (ping-pong b0/b1)
// so each tile's L2 latency hides under the previous tile's MFMA+epilogue.
// acc split into two 32-reg halves to keep peak VGPR < 256 (2 waves/SIMD).
// B's 1/16 unscale via MX B-scale (E8M0 0x7B = 2^-4, exact).
__global__ __launch_bounds__(256, 2) void k_gemm(
        const unsigned char* __restrict__ EF,
        const unsigned char* __restrict__ BF,
        const float* __restrict__ badj,
        double* __restrict__ pGemm)
{
    const int tid  = threadIdx.x;
    const int wave = tid >> 6;
    const int lane = tid & 63;
    const int rg   = blockIdx.x >> 3;     // 256-row group (0..63)
    const int cg   = blockIdx.x & 7;      // 512-col group (0..7)
    const int ag0  = rg * 16 + wave * 4;  // A 16-row group base
    const int r16  = lane & 15;

    i32x8 af[2][4];
    #pragma unroll
    for (int s = 0; s < 2; ++s)
        #pragma unroll
        for (int mi = 0; mi < 4; ++mi)
            af[s][mi] = *(const i32x8*)(EF + (size_t)(ag0 + mi) * 4096
                                        + s * 2048 + lane * 32);

    float lsum = 0.0f;

    auto load_b = [&](i32x8 (&bf)[2][4], int j) {
        const int bg0 = cg * 32 + j * 4;
        #pragma unroll
        for (int s = 0; s < 2; ++s)
            #pragma unroll
            for (int ni = 0; ni < 4; ++ni)
                bf[s][ni] = *(const i32x8*)(BF + (size_t)(bg0 + ni) * 4096
                                            + s * 2048 + lane * 32);
    };

    auto compute_j = [&](const i32x8 (&bf)[2][4], int j) {
        float ba[4];
        #pragma unroll
        for (int ni = 0; ni < 4; ++ni)
            ba[ni] = badj[cg * 512 + j * 64 + ni * 16 + r16];
        #pragma unroll
        for (int half = 0; half < 2; ++half) {
            f32x4 acc[2][4] = {};
            #pragma unroll
            for (int s = 0; s < 2; ++s)
                #pragma unroll
                for (int mi = 0; mi < 2; ++mi)
                    #pragma unroll
                    for (int ni = 0; ni < 4; ++ni)
                        acc[mi][ni] = __builtin_amdgcn_mfma_scale_f32_16x16x128_f8f6f4(
                            af[s][half * 2 + mi], bf[s][ni], acc[mi][ni],
                            0, 0,                 // cbsz=fp8, blgp=fp8
                            0, 0x7F7F7F7F,        // scale A = 2^0
                            0, 0x7B7B7B7B);       // scale B = 2^-4 (undo W*16)
            #pragma unroll
            for (int ni = 0; ni < 4; ++ni)
                #pragma unroll
                for (int mi = 0; mi < 2; ++mi)
                    #pragma unroll
                    for (int r = 0; r < 4; ++r)
                        lsum += softplus_f(acc[mi][ni][r] + ba[ni]);
        }
    };

    i32x8 b0[2][4], b1[2][4];
    load_b(b0, 0);
    #pragma unroll 1
    for (int jj = 0; jj < 4; ++jj) {
        load_b(b1, jj * 2 + 1);              // prefetch while computing jj*2
        compute_j(b0, jj * 2);
        if (jj < 3) load_b(b0, jj * 2 + 2);  // prefetch while computing jj*2+1
        compute_j(b1, jj * 2 + 1);
    }

    #pragma unroll
    for (int off = 32; off > 0; off >>= 1) lsum += __shfl_down(lsum, off, 64);
    __shared__ float wsum[4];
    if (lane == 0) wsum[wave] = lsum;
    __syncthreads();
    if (tid == 0)
        pGemm[blockIdx.x] = (double)((wsum[0] + wsum[1]) + (wsum[2] + wsum[3]));
}

__global__ __launch_bounds__(256) void k_final(
        const double* __restrict__ pTrue, const double* __restrict__ pGemm,
        float* __restrict__ out)
{
    const int tid = threadIdx.x, wave = tid >> 6, lane = tid & 63;
    double s = 0.0;
    for (int i = tid; i < 1024; i += 256) s += pTrue[i];
    for (int i = tid; i < 512; i += 256) s += pGemm[i];
    #pragma unroll
    for (int off = 32; off > 0; off >>= 1) s += __shfl_down(s, off, 64);
    __shared__ double wsum[4];
    if (lane == 0) wsum[wave] = s;
    __syncthreads();
    if (tid == 0)
        out[0] = (float)(((wsum[0] + wsum[1]) + (wsum[2] + wsum[3]))
                         * (1.0 / (double)BATCH));
}

// ---------- launch ----------

extern "C" void kernel_launch(void* const* d_in, const int* in_sizes, int n_in,
                              void* d_out, int out_size, void* d_ws, size_t ws_size,
                              hipStream_t stream) {
    const float* emb  = (const float*)d_in[0];
    const int*   tgt  = (const int*)d_in[1];
    const int*   sids = (const int*)d_in[2];
    const float* W    = (const float*)d_in[3];
    const float* bias = (const float*)d_in[4];
    float* out = (float*)d_out;

    char* ws = (char*)d_ws;
    double*        pTrue = (double*)ws;                        // 1024 doubles
    double*        pGemm = (double*)(ws + 8192);               // 512 doubles
    float*         badj  = (float*)(ws + 40960);               // 16 KB
    unsigned char* BF    = (unsigned char*)(ws + 57344);       // 1 MB
    unsigned char* EF    = (unsigned char*)(ws + 57344 + 1048576); // 4 MB

    hipLaunchKernelGGL(k_prep, dim3(1088), dim3(256), 0, stream,
                       emb, tgt, sids, W, bias, EF, BF, badj, pTrue);
    hipLaunchKernelGGL(k_gemm, dim3(512), dim3(256), 0, stream,
                       EF, BF, badj, pGemm);
    hipLaunchKernelGGL(k_final, dim3(1), dim3(256), 0, stream,
                       pTrue, pGemm, out);
}

// Round 7
// 148.523 us; speedup vs baseline: 1.0483x; 1.0483x over previous
//
#include <hip/hip_runtime.h>
#include <cstdint>
#include <cstddef>

#define VOCAB 50000
#define EMBED 256
#define BATCH 16384
#define NSAMP 4096

typedef float f32x2 __attribute__((ext_vector_type(2)));
typedef float f32x4 __attribute__((ext_vector_type(4)));
typedef int   i32x8 __attribute__((ext_vector_type(8)));

// ---------- helpers ----------

// Pure-HW log(expected_count): no libm calls (validated round 6, absmax ~0).
__device__ __forceinline__ float log_expected_count(int id) {
    float u = 1.0f / ((float)id + 1.0f);
    float a = __logf(1.0f + u);
    float p = a * 0.09242324f;   // 1/log(50001)
    float ser = p * (1.0f + p * (0.5f + p * (0.33333333f + p * (0.25f + p * 0.2f))));
    float q = -(float)NSAMP * ser;
    return __logf(1.0f - __expf(q));
}

// scalar softplus (prep path)
__device__ __forceinline__ float softplus_f(float x) {
    float v = __expf(-fabsf(x));
    float p = fmaf(v, 0.03215845f, -0.13606275f);
    p = fmaf(v, p, 0.28947478f);
    p = fmaf(v, p, -0.49190896f);
    p = fmaf(v, p, 0.99949556f);
    return fmaxf(x, 0.0f) + v * p;
}

// packed softplus on 2 lanes-of-f32: targets v_pk_fma_f32 / v_pk_max_f32.
__device__ __forceinline__ f32x2 softplus2(f32x2 x) {
    f32x2 ax = __builtin_elementwise_max(x, -x);   // |x|
    f32x2 v;
    v.x = __expf(-ax.x);
    v.y = __expf(-ax.y);
    f32x2 p = v * 0.03215845f - 0.13606275f;
    p = v * p + 0.28947478f;
    p = v * p - 0.49190896f;
    p = v * p + 0.99949556f;
    f32x2 z = {0.0f, 0.0f};
    return __builtin_elementwise_max(x, z) + v * p;
}

// pack 4 floats -> 4 fp8 e4m3 bytes (HW cvt, OCP on gfx950)
__device__ __forceinline__ int pk4_fp8(float a, float b, float c, float d) {
    int v = __builtin_amdgcn_cvt_pk_fp8_f32(a, b, 0, false);
    v = __builtin_amdgcn_cvt_pk_fp8_f32(c, d, v, true);
    return v;
}

// Fragment-order layout for an R x 256 fp8 matrix:
//   offset(r,k) = (r>>4)*4096 + (k>>5)*512 + (r&15)*32 + (k&31)
// Wave frag (group g, k-step s): contiguous 2KB at g*4096 + s*2048,
// per-lane 32B at +lane*32 (lane&15 = row, lane>>4 = k-quad).

// ---------- kernels ----------

// blocks [0,1024): true logits + E -> fp8 fragments (1 wave = 4 rows)
// blocks [1024,1088): gather W[sids] * 16 -> fp8 fragments + badj
// block 0 / tid 0 additionally zeroes acc + counter (safe: no one reads them
// until k_gemm, which starts after k_prep fully completes by stream order).
__global__ __launch_bounds__(256) void k_prep(
        const float* __restrict__ E, const int* __restrict__ tgt,
        const int* __restrict__ sids, const float* __restrict__ W,
        const float* __restrict__ bias,
        unsigned char* __restrict__ EF, unsigned char* __restrict__ BF,
        float* __restrict__ badj, double* __restrict__ pTrue,
        double* __restrict__ acc, unsigned int* __restrict__ counter)
{
    const int blk = blockIdx.x, tid = threadIdx.x;
    const int wave = tid >> 6, lane = tid & 63;

    if (blk == 0 && tid == 0) { *acc = 0.0; *counter = 0u; }

    if (blk < 1024) {
        float tsum = 0.0f;
        #pragma unroll
        for (int i = 0; i < 4; ++i) {
            int b = (blk * 4 + wave) + 4096 * i;
            int label = tgt[b];
            float4 e  = ((const float4*)(E + (size_t)b * EMBED))[lane];
            float4 wv = ((const float4*)(W + (size_t)label * EMBED))[lane];
            int pk = pk4_fp8(e.x, e.y, e.z, e.w);
            *(int*)(EF + ((b >> 4) * 4096 + (lane >> 3) * 512
                          + (b & 15) * 32 + (lane & 7) * 4)) = pk;
            float d = e.x * wv.x + e.y * wv.y + e.z * wv.z + e.w * wv.w;
            #pragma unroll
            for (int off = 32; off > 0; off >>= 1) d += __shfl_down(d, off, 64);
            if (lane == 0) {
                float tl = d + bias[label] - log_expected_count(label);
                tsum += softplus_f(-tl);
            }
        }
        __shared__ float ts[4];
        if (lane == 0) ts[wave] = tsum;
        __syncthreads();
        if (tid == 0) pTrue[blk] = (double)((ts[0] + ts[1]) + (ts[2] + ts[3]));
    } else {
        #pragma unroll
        for (int i = 0; i < 4; ++i) {
            int task = (blk - 1024) * 256 + tid + 16384 * i;
            int s = task >> 4, p = task & 15;   // p = 16B chunk, k = p*16
            int sid = sids[s];
            const float4* wr = (const float4*)(W + (size_t)sid * EMBED + p * 16);
            float4 w0 = wr[0], w1 = wr[1], w2 = wr[2], w3 = wr[3];
            int4 o;
            o.x = pk4_fp8(w0.x * 16.0f, w0.y * 16.0f, w0.z * 16.0f, w0.w * 16.0f);
            o.y = pk4_fp8(w1.x * 16.0f, w1.y * 16.0f, w1.z * 16.0f, w1.w * 16.0f);
            o.z = pk4_fp8(w2.x * 16.0f, w2.y * 16.0f, w2.z * 16.0f, w2.w * 16.0f);
            o.w = pk4_fp8(w3.x * 16.0f, w3.y * 16.0f, w3.z * 16.0f, w3.w * 16.0f);
            *(int4*)(BF + ((s >> 4) * 4096 + (p >> 1) * 512
                           + (s & 15) * 32 + (p & 1) * 16)) = o;
            if (p == 0) badj[s] = bias[sid] - log_expected_count(sid);
        }
    }
}

// GEMM: direct-register MX-fp8, no LDS (round-5 structure, known spill-free).
// A (64 rows) resident per wave; j-loop over 8 B-tiles, single B buffer.
// Packed-f32 softplus epilogue. Last-finishing block folds in pTrue partials
// and writes the final scalar (counter election) — no k_final launch.
// B's 1/16 unscale via MX B-scale (E8M0 0x7B = 2^-4, exact).
__global__ __launch_bounds__(256, 2) void k_gemm(
        const unsigned char* __restrict__ EF,
        const unsigned char* __restrict__ BF,
        const float* __restrict__ badj,
        const double* __restrict__ pTrue,
        double* __restrict__ acc, unsigned int* __restrict__ counter,
        float* __restrict__ out)
{
    const int tid  = threadIdx.x;
    const int wave = tid >> 6;
    const int lane = tid & 63;
    const int rg   = blockIdx.x >> 3;     // 256-row group (0..63)
    const int cg   = blockIdx.x & 7;      // 512-col group (0..7) == XCD affinity
    const int ag0  = rg * 16 + wave * 4;  // A 16-row group base
    const int r16  = lane & 15;

    i32x8 af[2][4];
    #pragma unroll
    for (int s = 0; s < 2; ++s)
        #pragma unroll
        for (int mi = 0; mi < 4; ++mi)
            af[s][mi] = *(const i32x8*)(EF + (size_t)(ag0 + mi) * 4096
                                        + s * 2048 + lane * 32);

    f32x2 ls2 = {0.0f, 0.0f};

    #pragma unroll 1
    for (int j = 0; j < 8; ++j) {
        const int bg0 = cg * 32 + j * 4;          // B 16-row group base
        i32x8 bf[2][4];
        #pragma unroll
        for (int s = 0; s < 2; ++s)
            #pragma unroll
            for (int ni = 0; ni < 4; ++ni)
                bf[s][ni] = *(const i32x8*)(BF + (size_t)(bg0 + ni) * 4096
                                            + s * 2048 + lane * 32);

        f32x4 a4[4][4] = {};
        #pragma unroll
        for (int s = 0; s < 2; ++s)
            #pragma unroll
            for (int mi = 0; mi < 4; ++mi)
                #pragma unroll
                for (int ni = 0; ni < 4; ++ni)
                    a4[mi][ni] = __builtin_amdgcn_mfma_scale_f32_16x16x128_f8f6f4(
                        af[s][mi], bf[s][ni], a4[mi][ni],
                        0, 0,                 // cbsz=fp8, blgp=fp8
                        0, 0x7F7F7F7F,        // scale A = 2^0
                        0, 0x7B7B7B7B);       // scale B = 2^-4 (undo W*16)

        // Epilogue: C/D col=lane&15, row=quad*4+r; packed 2-wide softplus
        #pragma unroll
        for (int ni = 0; ni < 4; ++ni) {
            const float ba = badj[cg * 512 + j * 64 + ni * 16 + r16];
            #pragma unroll
            for (int mi = 0; mi < 4; ++mi) {
                f32x2 x0 = {a4[mi][ni][0] + ba, a4[mi][ni][1] + ba};
                f32x2 x1 = {a4[mi][ni][2] + ba, a4[mi][ni][3] + ba};
                ls2 += softplus2(x0);
                ls2 += softplus2(x1);
            }
        }
    }

    float lsum = ls2.x + ls2.y;
    #pragma unroll
    for (int off = 32; off > 0; off >>= 1) lsum += __shfl_down(lsum, off, 64);
    __shared__ float wsum[4];
    __shared__ int last;
    if (lane == 0) wsum[wave] = lsum;
    __syncthreads();
    if (tid == 0) {
        atomicAdd(acc, (double)((wsum[0] + wsum[1]) + (wsum[2] + wsum[3])));
        __threadfence();
        unsigned int old = atomicAdd(counter, 1u);
        last = (old == 511u) ? 1 : 0;
    }
    __syncthreads();
    if (last) {
        // All 512 gemm sums are in *acc; fold in the 1024 prep partials.
        double s = 0.0;
        for (int i = tid; i < 1024; i += 256) s += pTrue[i];
        #pragma unroll
        for (int off = 32; off > 0; off >>= 1) s += __shfl_down(s, off, 64);
        __shared__ double dsum[4];
        if (lane == 0) dsum[wave] = s;
        __syncthreads();
        if (tid == 0) {
            double total = atomicAdd(acc, 0.0);   // coherent read of final acc
            total += (dsum[0] + dsum[1]) + (dsum[2] + dsum[3]);
            out[0] = (float)(total * (1.0 / (double)BATCH));
        }
    }
}

// ---------- launch ----------

extern "C" void kernel_launch(void* const* d_in, const int* in_sizes, int n_in,
                              void* d_out, int out_size, void* d_ws, size_t ws_size,
                              hipStream_t stream) {
    const float* emb  = (const float*)d_in[0];
    const int*   tgt  = (const int*)d_in[1];
    const int*   sids = (const int*)d_in[2];
    const float* W    = (const float*)d_in[3];
    const float* bias = (const float*)d_in[4];
    float* out = (float*)d_out;

    char* ws = (char*)d_ws;
    double*        acc     = (double*)ws;                      // 8 B
    unsigned int*  counter = (unsigned int*)(ws + 8);          // 4 B
    double*        pTrue   = (double*)(ws + 1024);             // 8 KB
    float*         badj    = (float*)(ws + 16384);             // 16 KB
    unsigned char* BF      = (unsigned char*)(ws + 65536);     // 1 MB
    unsigned char* EF      = (unsigned char*)(ws + 65536 + 1048576); // 4 MB

    hipLaunchKernelGGL(k_prep, dim3(1088), dim3(256), 0, stream,
                       emb, tgt, sids, W, bias, EF, BF, badj, pTrue, acc, counter);
    hipLaunchKernelGGL(k_gemm, dim3(512), dim3(256), 0, stream,
                       EF, BF, badj, pTrue, acc, counter, out);
}

// Round 8
// 137.366 us; speedup vs baseline: 1.1334x; 1.0812x over previous
//
#include <hip/hip_runtime.h>
#include <cstdint>
#include <cstddef>

#define VOCAB 50000
#define EMBED 256
#define BATCH 16384
#define NSAMP 4096

typedef float f32x4 __attribute__((ext_vector_type(4)));
typedef int   i32x8 __attribute__((ext_vector_type(8)));

// ---------- helpers ----------

// Pure-HW log(expected_count): no libm calls (validated r6/r7, absmax 0.0).
__device__ __forceinline__ float log_expected_count(int id) {
    float u = 1.0f / ((float)id + 1.0f);
    float a = __logf(1.0f + u);
    float p = a * 0.09242324f;   // 1/log(50001)
    float ser = p * (1.0f + p * (0.5f + p * (0.33333333f + p * (0.25f + p * 0.2f))));
    float q = -(float)NSAMP * ser;
    return __logf(1.0f - __expf(q));
}

// softplus(x) = max(x,0) + log1p(e^{-|x|}); deg-5 minimax (|err|<=1e-5)
__device__ __forceinline__ float softplus_f(float x) {
    float v = __expf(-fabsf(x));
    float p = fmaf(v, 0.03215845f, -0.13606275f);
    p = fmaf(v, p, 0.28947478f);
    p = fmaf(v, p, -0.49190896f);
    p = fmaf(v, p, 0.99949556f);
    return fmaxf(x, 0.0f) + v * p;
}

// pack 4 floats -> 4 fp8 e4m3 bytes (HW cvt, OCP on gfx950)
__device__ __forceinline__ int pk4_fp8(float a, float b, float c, float d) {
    int v = __builtin_amdgcn_cvt_pk_fp8_f32(a, b, 0, false);
    v = __builtin_amdgcn_cvt_pk_fp8_f32(c, d, v, true);
    return v;
}

// Fragment-order layout for an R x 256 fp8 matrix:
//   offset(r,k) = (r>>4)*4096 + (k>>5)*512 + (r&15)*32 + (k&31)
// Wave frag (group g, k-step s): contiguous 2KB at g*4096 + s*2048,
// per-lane 32B at +lane*32 (lane&15 = row, lane>>4 = k-quad).

// ---------- kernels ----------

// blocks [0,1024): true logits + E -> fp8 fragments (1 wave = 4 rows)
// blocks [1024,1088): gather W[sids] * 16 -> fp8 fragments + badj
__global__ __launch_bounds__(256) void k_prep(
        const float* __restrict__ E, const int* __restrict__ tgt,
        const int* __restrict__ sids, const float* __restrict__ W,
        const float* __restrict__ bias,
        unsigned char* __restrict__ EF, unsigned char* __restrict__ BF,
        float* __restrict__ badj, double* __restrict__ pTrue)
{
    const int blk = blockIdx.x, tid = threadIdx.x;
    const int wave = tid >> 6, lane = tid & 63;

    if (blk < 1024) {
        float tsum = 0.0f;
        #pragma unroll
        for (int i = 0; i < 4; ++i) {
            int b = (blk * 4 + wave) + 4096 * i;
            int label = tgt[b];
            float4 e  = ((const float4*)(E + (size_t)b * EMBED))[lane];
            float4 wv = ((const float4*)(W + (size_t)label * EMBED))[lane];
            int pk = pk4_fp8(e.x, e.y, e.z, e.w);
            *(int*)(EF + ((b >> 4) * 4096 + (lane >> 3) * 512
                          + (b & 15) * 32 + (lane & 7) * 4)) = pk;
            float d = e.x * wv.x + e.y * wv.y + e.z * wv.z + e.w * wv.w;
            #pragma unroll
            for (int off = 32; off > 0; off >>= 1) d += __shfl_down(d, off, 64);
            if (lane == 0) {
                float tl = d + bias[label] - log_expected_count(label);
                tsum += softplus_f(-tl);
            }
        }
        __shared__ float ts[4];
        if (lane == 0) ts[wave] = tsum;
        __syncthreads();
        if (tid == 0) pTrue[blk] = (double)((ts[0] + ts[1]) + (ts[2] + ts[3]));
    } else {
        #pragma unroll
        for (int i = 0; i < 4; ++i) {
            int task = (blk - 1024) * 256 + tid + 16384 * i;
            int s = task >> 4, p = task & 15;   // p = 16B chunk, k = p*16
            int sid = sids[s];
            const float4* wr = (const float4*)(W + (size_t)sid * EMBED + p * 16);
            float4 w0 = wr[0], w1 = wr[1], w2 = wr[2], w3 = wr[3];
            int4 o;
            o.x = pk4_fp8(w0.x * 16.0f, w0.y * 16.0f, w0.z * 16.0f, w0.w * 16.0f);
            o.y = pk4_fp8(w1.x * 16.0f, w1.y * 16.0f, w1.z * 16.0f, w1.w * 16.0f);
            o.z = pk4_fp8(w2.x * 16.0f, w2.y * 16.0f, w2.z * 16.0f, w2.w * 16.0f);
            o.w = pk4_fp8(w3.x * 16.0f, w3.y * 16.0f, w3.z * 16.0f, w3.w * 16.0f);
            *(int4*)(BF + ((s >> 4) * 4096 + (p >> 1) * 512
                           + (s & 15) * 32 + (p & 1) * 16)) = o;
            if (p == 0) badj[s] = bias[sid] - log_expected_count(sid);
        }
    }
}

// GEMM: direct-register MX-fp8, no LDS. A (64 rows) resident per wave across
// the 8-tile j-loop; single B buffer. Accumulators QUARTER-SPLIT (one mi-group
// of 4 f32x4 live at a time) so peak VGPR ~165 fits __launch_bounds__(256,3)
// -> 3 waves/SIMD for latency hiding; per-mi epilogue VALU interleaves with
// the next mi-group's MFMAs. B's 1/16 unscale via MX B-scale (0x7B = 2^-4).
__global__ __launch_bounds__(256, 3) void k_gemm(
        const unsigned char* __restrict__ EF,
        const unsigned char* __restrict__ BF,
        const float* __restrict__ badj,
        double* __restrict__ pGemm)
{
    const int tid  = threadIdx.x;
    const int wave = tid >> 6;
    const int lane = tid & 63;
    const int rg   = blockIdx.x >> 3;     // 256-row group (0..63)
    const int cg   = blockIdx.x & 7;      // 512-col group (0..7)
    const int ag0  = rg * 16 + wave * 4;  // A 16-row group base
    const int r16  = lane & 15;

    i32x8 af[2][4];
    #pragma unroll
    for (int s = 0; s < 2; ++s)
        #pragma unroll
        for (int mi = 0; mi < 4; ++mi)
            af[s][mi] = *(const i32x8*)(EF + (size_t)(ag0 + mi) * 4096
                                        + s * 2048 + lane * 32);

    float lsum = 0.0f;

    #pragma unroll 1
    for (int j = 0; j < 8; ++j) {
        const int bg0 = cg * 32 + j * 4;          // B 16-row group base
        i32x8 bf[2][4];
        #pragma unroll
        for (int s = 0; s < 2; ++s)
            #pragma unroll
            for (int ni = 0; ni < 4; ++ni)
                bf[s][ni] = *(const i32x8*)(BF + (size_t)(bg0 + ni) * 4096
                                            + s * 2048 + lane * 32);

        float ba[4];
        #pragma unroll
        for (int ni = 0; ni < 4; ++ni)
            ba[ni] = badj[cg * 512 + j * 64 + ni * 16 + r16];

        #pragma unroll
        for (int mi = 0; mi < 4; ++mi) {
            f32x4 acc[4] = {};
            #pragma unroll
            for (int s = 0; s < 2; ++s)
                #pragma unroll
                for (int ni = 0; ni < 4; ++ni)
                    acc[ni] = __builtin_amdgcn_mfma_scale_f32_16x16x128_f8f6f4(
                        af[s][mi], bf[s][ni], acc[ni],
                        0, 0,                 // cbsz=fp8, blgp=fp8
                        0, 0x7F7F7F7F,        // scale A = 2^0
                        0, 0x7B7B7B7B);       // scale B = 2^-4 (undo W*16)
            #pragma unroll
            for (int ni = 0; ni < 4; ++ni)
                #pragma unroll
                for (int r = 0; r < 4; ++r)
                    lsum += softplus_f(acc[ni][r] + ba[ni]);
        }
    }

    #pragma unroll
    for (int off = 32; off > 0; off >>= 1) lsum += __shfl_down(lsum, off, 64);
    __shared__ float wsum[4];
    if (lane == 0) wsum[wave] = lsum;
    __syncthreads();
    if (tid == 0)
        pGemm[blockIdx.x] = (double)((wsum[0] + wsum[1]) + (wsum[2] + wsum[3]));
}

__global__ __launch_bounds__(256) void k_final(
        const double* __restrict__ pTrue, const double* __restrict__ pGemm,
        float* __restrict__ out)
{
    const int tid = threadIdx.x, wave = tid >> 6, lane = tid & 63;
    double s = 0.0;
    for (int i = tid; i < 1024; i += 256) s += pTrue[i];
    for (int i = tid; i < 512; i += 256) s += pGemm[i];
    #pragma unroll
    for (int off = 32; off > 0; off >>= 1) s += __shfl_down(s, off, 64);
    __shared__ double wsum[4];
    if (lane == 0) wsum[wave] = s;
    __syncthreads();
    if (tid == 0)
        out[0] = (float)(((wsum[0] + wsum[1]) + (wsum[2] + wsum[3]))
                         * (1.0 / (double)BATCH));
}

// ---------- launch ----------

extern "C" void kernel_launch(void* const* d_in, const int* in_sizes, int n_in,
                              void* d_out, int out_size, void* d_ws, size_t ws_size,
                              hipStream_t stream) {
    const float* emb  = (const float*)d_in[0];
    const int*   tgt  = (const int*)d_in[1];
    const int*   sids = (const int*)d_in[2];
    const float* W    = (const float*)d_in[3];
    const float* bias = (const float*)d_in[4];
    float* out = (float*)d_out;

    char* ws = (char*)d_ws;
    double*        pTrue = (double*)ws;                        // 1024 doubles
    double*        pGemm = (double*)(ws + 8192);               // 512 doubles
    float*         badj  = (float*)(ws + 40960);               // 16 KB
    unsigned char* BF    = (unsigned char*)(ws + 57344);       // 1 MB
    unsigned char* EF    = (unsigned char*)(ws + 57344 + 1048576); // 4 MB

    hipLaunchKernelGGL(k_prep, dim3(1088), dim3(256), 0, stream,
                       emb, tgt, sids, W, bias, EF, BF, badj, pTrue);
    hipLaunchKernelGGL(k_gemm, dim3(512), dim3(256), 0, stream,
                       EF, BF, badj, pGemm);
    hipLaunchKernelGGL(k_final, dim3(1), dim3(256), 0, stream,
                       pTrue, pGemm, out);
}

// Round 9
// 135.702 us; speedup vs baseline: 1.1473x; 1.0123x over previous
//
#include <hip/hip_runtime.h>
#include <cstdint>
#include <cstddef>

#define VOCAB 50000
#define EMBED 256
#define BATCH 16384
#define NSAMP 4096

typedef float f32x4 __attribute__((ext_vector_type(4)));
typedef int   i32x8 __attribute__((ext_vector_type(8)));

// ---------- helpers ----------

// Pure-HW log(expected_count): no libm calls (validated r6-r8, absmax 0.0).
__device__ __forceinline__ float log_expected_count(int id) {
    float u = 1.0f / ((float)id + 1.0f);
    float a = __logf(1.0f + u);
    float p = a * 0.09242324f;   // 1/log(50001)
    float ser = p * (1.0f + p * (0.5f + p * (0.33333333f + p * (0.25f + p * 0.2f))));
    float q = -(float)NSAMP * ser;
    return __logf(1.0f - __expf(q));
}

// softplus(x) = max(x,0) + log1p(e^{-|x|}); deg-5 minimax (|err|<=1e-5)
__device__ __forceinline__ float softplus_f(float x) {
    float v = __expf(-fabsf(x));
    float p = fmaf(v, 0.03215845f, -0.13606275f);
    p = fmaf(v, p, 0.28947478f);
    p = fmaf(v, p, -0.49190896f);
    p = fmaf(v, p, 0.99949556f);
    return fmaxf(x, 0.0f) + v * p;
}

// pack 4 floats -> 4 fp8 e4m3 bytes (HW cvt, OCP on gfx950)
__device__ __forceinline__ int pk4_fp8(float a, float b, float c, float d) {
    int v = __builtin_amdgcn_cvt_pk_fp8_f32(a, b, 0, false);
    v = __builtin_amdgcn_cvt_pk_fp8_f32(c, d, v, true);
    return v;
}

// Fragment-order layout for an R x 256 fp8 matrix:
//   offset(r,k) = (r>>4)*4096 + (k>>5)*512 + (r&15)*32 + (k&31)
// Wave frag (group g, k-step s): contiguous 2KB at g*4096 + s*2048,
// per-lane 32B at +lane*32 (lane&15 = row, lane>>4 = k-quad).

// ---------- kernels ----------

// blocks [0,1024): true logits + E -> fp8 fragments (1 wave = 4 rows)
// blocks [1024,1088): gather W[sids] * 16 -> fp8 fragments + badj
__global__ __launch_bounds__(256) void k_prep(
        const float* __restrict__ E, const int* __restrict__ tgt,
        const int* __restrict__ sids, const float* __restrict__ W,
        const float* __restrict__ bias,
        unsigned char* __restrict__ EF, unsigned char* __restrict__ BF,
        float* __restrict__ badj, double* __restrict__ pTrue)
{
    const int blk = blockIdx.x, tid = threadIdx.x;
    const int wave = tid >> 6, lane = tid & 63;

    if (blk < 1024) {
        float tsum = 0.0f;
        #pragma unroll
        for (int i = 0; i < 4; ++i) {
            int b = (blk * 4 + wave) + 4096 * i;
            int label = tgt[b];
            float4 e  = ((const float4*)(E + (size_t)b * EMBED))[lane];
            float4 wv = ((const float4*)(W + (size_t)label * EMBED))[lane];
            int pk = pk4_fp8(e.x, e.y, e.z, e.w);
            *(int*)(EF + ((b >> 4) * 4096 + (lane >> 3) * 512
                          + (b & 15) * 32 + (lane & 7) * 4)) = pk;
            float d = e.x * wv.x + e.y * wv.y + e.z * wv.z + e.w * wv.w;
            #pragma unroll
            for (int off = 32; off > 0; off >>= 1) d += __shfl_down(d, off, 64);
            if (lane == 0) {
                float tl = d + bias[label] - log_expected_count(label);
                tsum += softplus_f(-tl);
            }
        }
        __shared__ float ts[4];
        if (lane == 0) ts[wave] = tsum;
        __syncthreads();
        if (tid == 0) pTrue[blk] = (double)((ts[0] + ts[1]) + (ts[2] + ts[3]));
    } else {
        #pragma unroll
        for (int i = 0; i < 4; ++i) {
            int task = (blk - 1024) * 256 + tid + 16384 * i;
            int s = task >> 4, p = task & 15;   // p = 16B chunk, k = p*16
            int sid = sids[s];
            const float4* wr = (const float4*)(W + (size_t)sid * EMBED + p * 16);
            float4 w0 = wr[0], w1 = wr[1], w2 = wr[2], w3 = wr[3];
            int4 o;
            o.x = pk4_fp8(w0.x * 16.0f, w0.y * 16.0f, w0.z * 16.0f, w0.w * 16.0f);
            o.y = pk4_fp8(w1.x * 16.0f, w1.y * 16.0f, w1.z * 16.0f, w1.w * 16.0f);
            o.z = pk4_fp8(w2.x * 16.0f, w2.y * 16.0f, w2.z * 16.0f, w2.w * 16.0f);
            o.w = pk4_fp8(w3.x * 16.0f, w3.y * 16.0f, w3.z * 16.0f, w3.w * 16.0f);
            *(int4*)(BF + ((s >> 4) * 4096 + (p >> 1) * 512
                           + (s & 15) * 32 + (p & 1) * 16)) = o;
            if (p == 0) badj[s] = bias[sid] - log_expected_count(sid);
        }
    }
}

// GEMM: direct-register MX-fp8, no LDS (r8 inner structure, spill-free).
// Grid 1024: blk>>4 = 256-row group, blk&15 = 256-col group -> 4 blocks/CU
// available (r8's 512 grid capped the machine at 2 waves/SIMD; counters showed
// MfmaUtil 16 + VALUBusy 47 + Occupancy 19 = starved for waves, not work).
// Quarter-split accumulators keep peak regs ~(256,3)-compatible.
__global__ __launch_bounds__(256, 3) void k_gemm(
        const unsigned char* __restrict__ EF,
        const unsigned char* __restrict__ BF,
        const float* __restrict__ badj,
        double* __restrict__ pGemm)
{
    const int tid  = threadIdx.x;
    const int wave = tid >> 6;
    const int lane = tid & 63;
    const int rg   = blockIdx.x >> 4;     // 256-row group (0..63)
    const int cg   = blockIdx.x & 15;     // 256-col group (0..15)
    const int ag0  = rg * 16 + wave * 4;  // A 16-row group base
    const int r16  = lane & 15;

    i32x8 af[2][4];
    #pragma unroll
    for (int s = 0; s < 2; ++s)
        #pragma unroll
        for (int mi = 0; mi < 4; ++mi)
            af[s][mi] = *(const i32x8*)(EF + (size_t)(ag0 + mi) * 4096
                                        + s * 2048 + lane * 32);

    float lsum = 0.0f;

    #pragma unroll 1
    for (int j = 0; j < 4; ++j) {
        const int bg0 = cg * 16 + j * 4;          // B 16-row group base
        i32x8 bf[2][4];
        #pragma unroll
        for (int s = 0; s < 2; ++s)
            #pragma unroll
            for (int ni = 0; ni < 4; ++ni)
                bf[s][ni] = *(const i32x8*)(BF + (size_t)(bg0 + ni) * 4096
                                            + s * 2048 + lane * 32);

        float ba[4];
        #pragma unroll
        for (int ni = 0; ni < 4; ++ni)
            ba[ni] = badj[cg * 256 + j * 64 + ni * 16 + r16];

        #pragma unroll
        for (int mi = 0; mi < 4; ++mi) {
            f32x4 acc[4] = {};
            #pragma unroll
            for (int s = 0; s < 2; ++s)
                #pragma unroll
                for (int ni = 0; ni < 4; ++ni)
                    acc[ni] = __builtin_amdgcn_mfma_scale_f32_16x16x128_f8f6f4(
                        af[s][mi], bf[s][ni], acc[ni],
                        0, 0,                 // cbsz=fp8, blgp=fp8
                        0, 0x7F7F7F7F,        // scale A = 2^0
                        0, 0x7B7B7B7B);       // scale B = 2^-4 (undo W*16)
            #pragma unroll
            for (int ni = 0; ni < 4; ++ni)
                #pragma unroll
                for (int r = 0; r < 4; ++r)
                    lsum += softplus_f(acc[ni][r] + ba[ni]);
        }
    }

    #pragma unroll
    for (int off = 32; off > 0; off >>= 1) lsum += __shfl_down(lsum, off, 64);
    __shared__ float wsum[4];
    if (lane == 0) wsum[wave] = lsum;
    __syncthreads();
    if (tid == 0)
        pGemm[blockIdx.x] = (double)((wsum[0] + wsum[1]) + (wsum[2] + wsum[3]));
}

__global__ __launch_bounds__(256) void k_final(
        const double* __restrict__ pTrue, const double* __restrict__ pGemm,
        float* __restrict__ out)
{
    const int tid = threadIdx.x, wave = tid >> 6, lane = tid & 63;
    double s = 0.0;
    for (int i = tid; i < 1024; i += 256) s += pTrue[i];
    for (int i = tid; i < 1024; i += 256) s += pGemm[i];
    #pragma unroll
    for (int off = 32; off > 0; off >>= 1) s += __shfl_down(s, off, 64);
    __shared__ double wsum[4];
    if (lane == 0) wsum[wave] = s;
    __syncthreads();
    if (tid == 0)
        out[0] = (float)(((wsum[0] + wsum[1]) + (wsum[2] + wsum[3]))
                         * (1.0 / (double)BATCH));
}

// ---------- launch ----------

extern "C" void kernel_launch(void* const* d_in, const int* in_sizes, int n_in,
                              void* d_out, int out_size, void* d_ws, size_t ws_size,
                              hipStream_t stream) {
    const float* emb  = (const float*)d_in[0];
    const int*   tgt  = (const int*)d_in[1];
    const int*   sids = (const int*)d_in[2];
    const float* W    = (const float*)d_in[3];
    const float* bias = (const float*)d_in[4];
    float* out = (float*)d_out;

    char* ws = (char*)d_ws;
    double*        pTrue = (double*)ws;                        // 1024 doubles
    double*        pGemm = (double*)(ws + 8192);               // 1024 doubles
    float*         badj  = (float*)(ws + 40960);               // 16 KB
    unsigned char* BF    = (unsigned char*)(ws + 57344);       // 1 MB
    unsigned char* EF    = (unsigned char*)(ws + 57344 + 1048576); // 4 MB

    hipLaunchKernelGGL(k_prep, dim3(1088), dim3(256), 0, stream,
                       emb, tgt, sids, W, bias, EF, BF, badj, pTrue);
    hipLaunchKernelGGL(k_gemm, dim3(1024), dim3(256), 0, stream,
                       EF, BF, badj, pGemm);
    hipLaunchKernelGGL(k_final, dim3(1), dim3(256), 0, stream,
                       pTrue, pGemm, out);
}